// Round 15
// baseline (59.590 us; speedup 1.0000x reference)
//
#include <hip/hip_runtime.h>

#define NUM_NETS     100000
#define PINS_PER_NET 5
#define NUM_PINS     (NUM_NETS * PINS_PER_NET)
#define NB           512
#define BIN_H        1.953125f          /* 1000/512, exact in fp32 */
#define INV_H        0.512f             /* 512/1000 */
#define OUT_SCALE    (1.0f / 195.3125f) /* 1/(BIN_SIZE_X * 100 tracks) */

#define SW           8                  /* stripe width (x bins) */
#define NSTRIPES     (NB / SW)          /* 64 */
#define CAP          24576              /* items per stripe bucket (worst ~16K) */
#define NSL          4                  /* y-slices per stripe */
#define SLH2         128                /* bins per slice */

#define FXS          2097152.0f         /* 2^21 fixed-point scale */
#define INV_FXS      (1.0f / 2097152.0f)

// ---------------------------------------------------------------------------
// K_0: zero the 64 stripe cursors.
// ---------------------------------------------------------------------------
__global__ void zero_kernel(int* __restrict__ gcur) {
    gcur[threadIdx.x] = 0;
}

// ---------------------------------------------------------------------------
// K_A: bbox + emit 16B items {x, y, s*wh, s*wv} into per-stripe buckets.
// (unchanged from R13)
// ---------------------------------------------------------------------------
__global__ __launch_bounds__(256) void bbox_emit_kernel(
        const float* __restrict__ pin_pos,
        const int*   __restrict__ flat_netpin,
        const float* __restrict__ net_weights,
        int* __restrict__ gcur,
        float4* __restrict__ bucket) {
    __shared__ int lcnt[NSTRIPES];
    __shared__ int lbase[NSTRIPES];
    int tid = threadIdx.x;
    if (tid < NSTRIPES) lcnt[tid] = 0;
    __syncthreads();

    int n = blockIdx.x * 256 + tid;
    bool valid = n < NUM_NETS;
    float xmn = 1e30f, xmx = -1e30f, ymn = 1e30f, ymx = -1e30f;
    float wh = 0.f, wv = 0.f;
    int kx1 = 0, kx2 = 0;
    if (valid) {
#pragma unroll
        for (int p = 0; p < PINS_PER_NET; ++p) {
            int pi  = flat_netpin[n * PINS_PER_NET + p];
            float x = pin_pos[pi];
            float y = pin_pos[NUM_PINS + pi];
            xmn = fminf(xmn, x); xmx = fmaxf(xmx, x);
            ymn = fminf(ymn, y); ymx = fmaxf(ymx, y);
        }
        float w = net_weights[n];
        wh = w / (ymx - ymn);
        wv = w / (xmx - xmn);
        kx1 = min(NB - 1, (int)(xmn * INV_H));
        kx2 = min(NB - 1, (int)(xmx * INV_H));
#pragma unroll
        for (int cx = 0; cx < 2; ++cx) {
            int kx = cx ? kx2 : kx1;
            int s0 = kx >> 3;
            atomicAdd(&lcnt[s0], 2);
            if (kx + 1 < NB && ((kx + 1) >> 3) != s0)
                atomicAdd(&lcnt[(kx + 1) >> 3], 2);
        }
    }
    __syncthreads();
    if (tid < NSTRIPES) {
        lbase[tid] = atomicAdd(&gcur[tid], lcnt[tid]);
        lcnt[tid] = 0;
    }
    __syncthreads();
    if (valid) {
#pragma unroll
        for (int cx = 0; cx < 2; ++cx) {
            int   kx = cx ? kx2 : kx1;
            float xc = cx ? xmx : xmn;
            int s0 = kx >> 3;
            int s1 = (kx + 1 < NB) ? ((kx + 1) >> 3) : s0;
#pragma unroll
            for (int cy = 0; cy < 2; ++cy) {
                float yc = cy ? ymx : ymn;
                float sg = ((cx ^ cy) ? -1.0f : 1.0f);
                float4 item = make_float4(xc, yc, sg * wh, sg * wv);
                {
                    int rank = atomicAdd(&lcnt[s0], 1);
                    int pos  = lbase[s0] + rank;
                    if (pos < CAP) bucket[(size_t)s0 * CAP + pos] = item;
                }
                if (s1 != s0) {
                    int rank = atomicAdd(&lcnt[s1], 1);
                    int pos  = lbase[s1] + rank;
                    if (pos < CAP) bucket[(size_t)s1 * CAP + pos] = item;
                }
            }
        }
    }
}

// ---------------------------------------------------------------------------
// K_B: slice kernel. Block = (stripe st, y-slice h). Reads whole stripe
// bucket (4x redundant, L2/L3-cheap), keeps its 8x128 quarter, int-atomic
// accumulate, then outputs:
//   C   = 2D prefix within (stripe x slice)      -> UpH/UpV
//   ct  = unscanned x-totals per y               -> ctH/ctV [64][512]
//   r   = x-scanned slice row-sums (8 floats)    -> rH/rV   [64][4][8]
// ---------------------------------------------------------------------------
__global__ __launch_bounds__(1024) void slice_kernel(
        const float4* __restrict__ bucket,
        const int* __restrict__ gcur,
        float* __restrict__ UpH, float* __restrict__ UpV,
        float* __restrict__ ctH, float* __restrict__ ctV,
        float* __restrict__ rH,  float* __restrict__ rV) {
    __shared__ int   acc[2 * SW * SLH2];        /* 8 KB: H then V */
    __shared__ float rtmp[16];
    __shared__ float rsH[8], rsV[8];
    __shared__ float wscH[8], wscV[8];
    int bid = blockIdx.x;
    int st  = bid >> 2;
    int h   = bid & 3;
    int tid = threadIdx.x;
    int x0  = st * SW;
    int y0  = h * SLH2;
    int* accH = acc;
    int* accV = acc + SW * SLH2;

    for (int k = tid; k < 2 * SW * SLH2; k += 1024) acc[k] = 0;
    __syncthreads();

    /* ---- accumulate (filter to this y-slice) ---- */
    int cnt = min(gcur[st], CAP);
    const float4* bk = bucket + (size_t)st * CAP;
    for (int q = tid; q < cnt; q += 1024) {
        float4 it = bk[q];
        int kx = min(NB - 1, (int)(it.x * INV_H));
        int ky = min(NB - 1, (int)(it.y * INV_H));
        int gy = ky - y0;
        if ((unsigned)(gy + 1) > (unsigned)SLH2) continue;  /* gy in [-1,128] */
        float dx0 = (kx + 1) * BIN_H - it.x;
        float dx1 = it.x - kx * BIN_H;
        float dy0 = (ky + 1) * BIN_H - it.y;
        float dy1 = it.y - ky * BIN_H;
        bool ok0 = (unsigned)gy < (unsigned)SLH2;
        bool ok1 = (ky + 1 < NB) && ((unsigned)(gy + 1) < (unsigned)SLH2);
        int c = kx - x0;
#pragma unroll
        for (int cc = 0; cc < 2; ++cc) {
            int col = c + cc;
            if ((unsigned)col < SW) {
                float dx = cc ? dx1 : dx0;
                if (ok0) {
                    int b = col * SLH2 + gy;
                    atomicAdd(&accH[b], __float2int_rn(it.z * dx * dy0 * FXS));
                    atomicAdd(&accV[b], __float2int_rn(it.w * dx * dy0 * FXS));
                }
                if (ok1) {
                    int b = col * SLH2 + gy + 1;
                    atomicAdd(&accH[b], __float2int_rn(it.z * dx * dy1 * FXS));
                    atomicAdd(&accV[b], __float2int_rn(it.w * dx * dy1 * FXS));
                }
            }
        }
    }
    __syncthreads();

    /* ---- convert int -> float in place ---- */
    float* fH = (float*)accH;
    float* fV = (float*)accV;
    for (int k = tid; k < 2 * SW * SLH2; k += 1024)
        ((float*)acc)[k] = (float)acc[k] * INV_FXS;
    __syncthreads();

    int row  = tid >> 7;           /* 0..7 */
    int ly   = tid & 127;
    int lane = tid & 63;
    int wh2  = (tid >> 6) & 1;     /* wave-half within row */

    /* ---- slice row-sums (unscanned) -> x-scan -> rH/rV ---- */
    {
        float v = fH[tid];
#pragma unroll
        for (int o = 1; o < 64; o <<= 1) v += __shfl_xor(v, o);
        if (lane == 0) rtmp[tid >> 6] = v;
        __syncthreads();
        if (tid < 8) rsH[tid] = rtmp[2 * tid] + rtmp[2 * tid + 1];
        __syncthreads();
        v = fV[tid];
#pragma unroll
        for (int o = 1; o < 64; o <<= 1) v += __shfl_xor(v, o);
        if (lane == 0) rtmp[tid >> 6] = v;
        __syncthreads();
        if (tid < 8) rsV[tid] = rtmp[2 * tid] + rtmp[2 * tid + 1];
        __syncthreads();
        if (tid == 0) {
            float f = 0.f;
#pragma unroll
            for (int x = 0; x < SW; ++x) { f += rsH[x]; rH[(st * NSL + h) * SW + x] = f; }
            f = 0.f;
#pragma unroll
            for (int x = 0; x < SW; ++x) { f += rsV[x]; rV[(st * NSL + h) * SW + x] = f; }
        }
    }

    /* ---- ct: unscanned x-totals per y ---- */
    if (tid < SLH2) {
        float s = 0.f;
#pragma unroll
        for (int x = 0; x < SW; ++x) s += fH[x * SLH2 + tid];
        ctH[st * NB + y0 + tid] = s;
    } else if (tid < 2 * SLH2) {
        int yy = tid - SLH2;
        float s = 0.f;
#pragma unroll
        for (int x = 0; x < SW; ++x) s += fV[x * SLH2 + yy];
        ctV[st * NB + y0 + yy] = s;
    }
    __syncthreads();

    /* ---- y-scan within slice, per row (128 wide = 2 waves) ---- */
    {
        float v = fH[tid];
#pragma unroll
        for (int o = 1; o < 64; o <<= 1) {
            float a = __shfl_up(v, o);
            if (lane >= o) v += a;
        }
        if (lane == 63 && wh2 == 0) wscH[row] = v;
        float u = fV[tid];
#pragma unroll
        for (int o = 1; o < 64; o <<= 1) {
            float a = __shfl_up(u, o);
            if (lane >= o) u += a;
        }
        if (lane == 63 && wh2 == 0) wscV[row] = u;
        __syncthreads();
        if (wh2 == 1) { v += wscH[row]; u += wscV[row]; }
        fH[tid] = v;
        fV[tid] = u;
        __syncthreads();
    }

    /* ---- x-scan across the 8 rows, per y ---- */
    if (tid < SLH2) {
        float f = 0.f;
#pragma unroll
        for (int x = 0; x < SW; ++x) {
            int i = x * SLH2 + tid;
            f += fH[i]; fH[i] = f;
        }
    } else if (tid < 2 * SLH2) {
        int yy = tid - SLH2;
        float f = 0.f;
#pragma unroll
        for (int x = 0; x < SW; ++x) {
            int i = x * SLH2 + yy;
            f += fV[i]; fV[i] = f;
        }
    }
    __syncthreads();

    /* ---- write C (2D prefix within stripe x slice) ---- */
    {
        int gi = (x0 + row) * NB + y0 + ly;
        UpH[gi] = fH[tid];
        UpV[gi] = fV[tid];
    }
}

// ---------------------------------------------------------------------------
// K_C: finish. Block = stripe, thread = y (512).
// A[y] = y-scan of sum_{s2<st} ct[s2][y]  (cross-stripe term)
// out  = clip(max(|C + r-prefix + A|)^2)
// ---------------------------------------------------------------------------
__global__ __launch_bounds__(512) void finish_kernel(
        const float* __restrict__ UpH, const float* __restrict__ UpV,
        const float* __restrict__ ctH, const float* __restrict__ ctV,
        const float* __restrict__ rH,  const float* __restrict__ rV,
        float* __restrict__ out) {
    __shared__ float wsc[16];
    int st = blockIdx.x;
    int y  = threadIdx.x;
    int lane = y & 63, wid = y >> 6;      /* 8 waves */

    float colH = 0.f, colV = 0.f;
    for (int s2 = 0; s2 < st; ++s2) {
        colH += ctH[s2 * NB + y];
        colV += ctV[s2 * NB + y];
    }
    /* block-wide inclusive y-scan of colH/colV */
#pragma unroll
    for (int o = 1; o < 64; o <<= 1) {
        float a = __shfl_up(colH, o);
        float b = __shfl_up(colV, o);
        if (lane >= o) { colH += a; colV += b; }
    }
    if (lane == 63) { wsc[wid] = colH; wsc[8 + wid] = colV; }
    __syncthreads();
    float oh = 0.f, ov = 0.f;
    for (int j = 0; j < wid; ++j) { oh += wsc[j]; ov += wsc[8 + j]; }
    float AH = colH + oh;
    float AV = colV + ov;

    /* r-prefix over slices below this y's slice */
    int h = y >> 7;
    float rpH[SW], rpV[SW];
#pragma unroll
    for (int x = 0; x < SW; ++x) { rpH[x] = 0.f; rpV[x] = 0.f; }
    for (int h2 = 0; h2 < h; ++h2) {
#pragma unroll
        for (int x = 0; x < SW; ++x) {
            rpH[x] += rH[(st * NSL + h2) * SW + x];
            rpV[x] += rV[(st * NSL + h2) * SW + x];
        }
    }

#pragma unroll
    for (int x = 0; x < SW; ++x) {
        int i = (st * SW + x) * NB + y;
        float hv = fabsf(UpH[i] + rpH[x] + AH) * OUT_SCALE;
        float vv = fabsf(UpV[i] + rpV[x] + AV) * OUT_SCALE;
        float m = fmaxf(hv, vv);
        out[i] = fminf(fmaxf(m * m, 0.5f), 2.0f);
    }
}

// ---------------------------------------------------------------------------
// Fallback (tiny workspace): global-atomic scatter + scans
// ---------------------------------------------------------------------------
__global__ void scatter_kernel(const float* __restrict__ pin_pos,
                               const int*   __restrict__ flat_netpin,
                               const float* __restrict__ net_weights,
                               float* __restrict__ Uh,
                               float* __restrict__ Uv) {
    int n = blockIdx.x * blockDim.x + threadIdx.x;
    if (n >= NUM_NETS) return;
    float xmn = 1e30f, xmx = -1e30f, ymn = 1e30f, ymx = -1e30f;
#pragma unroll
    for (int p = 0; p < PINS_PER_NET; ++p) {
        int pi  = flat_netpin[n * PINS_PER_NET + p];
        float x = pin_pos[pi];
        float y = pin_pos[NUM_PINS + pi];
        xmn = fminf(xmn, x); xmx = fmaxf(xmx, x);
        ymn = fminf(ymn, y); ymx = fmaxf(ymx, y);
    }
    float w  = net_weights[n];
    float wh = w / (ymx - ymn), wv = w / (xmx - xmn);
    int kx1 = min(NB - 1, (int)(xmn * INV_H));
    int kx2 = min(NB - 1, (int)(xmx * INV_H));
    int ky1 = min(NB - 1, (int)(ymn * INV_H));
    int ky2 = min(NB - 1, (int)(ymx * INV_H));
    int   xi[4] = { kx1, kx1 + 1, kx2, kx2 + 1 };
    float xv[4] = { (kx1 + 1) * BIN_H - xmn,  xmn - kx1 * BIN_H,
                    xmx - (kx2 + 1) * BIN_H,  kx2 * BIN_H - xmx };
    int   yi[4] = { ky1, ky1 + 1, ky2, ky2 + 1 };
    float yv[4] = { (ky1 + 1) * BIN_H - ymn,  ymn - ky1 * BIN_H,
                    ymx - (ky2 + 1) * BIN_H,  ky2 * BIN_H - ymx };
#pragma unroll
    for (int a = 0; a < 4; ++a) {
        if (xi[a] >= NB) continue;
#pragma unroll
        for (int b2 = 0; b2 < 4; ++b2) {
            if (yi[b2] >= NB) continue;
            float prod = xv[a] * yv[b2];
            atomicAdd(&Uh[xi[a] * NB + yi[b2]], wh * prod);
            atomicAdd(&Uv[xi[a] * NB + yi[b2]], wv * prod);
        }
    }
}

__global__ void fb_rowscan_kernel(float* __restrict__ Uh, float* __restrict__ Uv) {
    __shared__ float sh[NB];
    __shared__ float sv[NB];
    int rr = blockIdx.x, t = threadIdx.x;
    sh[t] = Uh[rr * NB + t];
    sv[t] = Uv[rr * NB + t];
    __syncthreads();
#pragma unroll
    for (int off = 1; off < NB; off <<= 1) {
        float a = (t >= off) ? sh[t - off] : 0.0f;
        float b = (t >= off) ? sv[t - off] : 0.0f;
        __syncthreads();
        sh[t] += a; sv[t] += b;
        __syncthreads();
    }
    Uh[rr * NB + t] = sh[t];
    Uv[rr * NB + t] = sv[t];
}

__global__ void fb_colscan_kernel(const float* __restrict__ Uh,
                                  const float* __restrict__ Uv,
                                  float* __restrict__ out) {
    int t = blockIdx.x * blockDim.x + threadIdx.x;
    if (t >= NB) return;
    float sh = 0.f, sv = 0.f;
    for (int i = 0; i < NB; ++i) {
        sh += Uh[i * NB + t];
        sv += Uv[i * NB + t];
        float h = fabsf(sh) * OUT_SCALE;
        float v = fabsf(sv) * OUT_SCALE;
        float m = fmaxf(h, v);
        out[i * NB + t] = fminf(fmaxf(m * m, 0.5f), 2.0f);
    }
}

extern "C" void kernel_launch(void* const* d_in, const int* in_sizes, int n_in,
                              void* d_out, int out_size, void* d_ws, size_t ws_size,
                              hipStream_t stream) {
    const float* pin_pos     = (const float*)d_in[0];
    const int*   flat_netpin = (const int*)d_in[2];
    const float* net_weights = (const float*)d_in[3];
    float* out = (float*)d_out;
    float* ws  = (float*)d_ws;

    /* layout (floats): gcur[64] | bucket[64*CAP*4] | ctH[64*512] | ctV[64*512]
       | rH[64*4*8] | rV[64*4*8] | UpH[512*512] | UpV[512*512]   (~27.6 MB) */
    const size_t o_cur = 0;
    const size_t o_bkt = 64;
    const size_t o_ctH = o_bkt + (size_t)NSTRIPES * CAP * 4;
    const size_t o_ctV = o_ctH + (size_t)NSTRIPES * NB;
    const size_t o_rH  = o_ctV + (size_t)NSTRIPES * NB;
    const size_t o_rV  = o_rH + (size_t)NSTRIPES * NSL * SW;
    const size_t o_UpH = o_rV + (size_t)NSTRIPES * NSL * SW;
    const size_t o_UpV = o_UpH + (size_t)NB * NB;
    const size_t need  = o_UpV + (size_t)NB * NB;

    if (ws_size < need * sizeof(float)) {
        float* Uh = ws;
        float* Uv = ws + (size_t)NB * NB;
        hipMemsetAsync(ws, 0, 2 * (size_t)NB * NB * sizeof(float), stream);
        scatter_kernel<<<(NUM_NETS + 255) / 256, 256, 0, stream>>>(
            pin_pos, flat_netpin, net_weights, Uh, Uv);
        fb_rowscan_kernel<<<NB, NB, 0, stream>>>(Uh, Uv);
        fb_colscan_kernel<<<2, 256, 0, stream>>>(Uh, Uv, out);
        return;
    }

    int*    gcur   = (int*)(ws + o_cur);
    float4* bucket = (float4*)(ws + o_bkt);
    float*  ctH    = ws + o_ctH;
    float*  ctV    = ws + o_ctV;
    float*  rH     = ws + o_rH;
    float*  rV     = ws + o_rV;
    float*  UpH    = ws + o_UpH;
    float*  UpV    = ws + o_UpV;

    zero_kernel<<<1, NSTRIPES, 0, stream>>>(gcur);

    bbox_emit_kernel<<<(NUM_NETS + 255) / 256, 256, 0, stream>>>(
        pin_pos, flat_netpin, net_weights, gcur, bucket);

    slice_kernel<<<NSTRIPES * NSL, 1024, 0, stream>>>(
        bucket, gcur, UpH, UpV, ctH, ctV, rH, rV);

    finish_kernel<<<NSTRIPES, 512, 0, stream>>>(UpH, UpV, ctH, ctV, rH, rV, out);
}